// Round 8
// baseline (148.438 us; speedup 1.0000x reference)
//
#include <hip/hip_runtime.h>

// 8 lanes per batch element; 2 hidden units per lane packed as float2 (VOP3P).
// Fast steps advance q3=r*V3, q4=r*V4 directly by a 2nd-order Taylor in a-space
// (shortest possible cross-step chain); exact exp2+rcp resync every RS steps.
// Outputs are accumulated in registers and stored in bursts per chunk.
#define LPE 8
#define CH 16   // steps per prefetch chunk
#define RS 4    // resync period (must divide CH)

typedef float v2f __attribute__((ext_vector_type(2)));

#if __has_builtin(__builtin_amdgcn_exp2f)
  #define EXP2F(x) __builtin_amdgcn_exp2f(x)
#else
  #define EXP2F(x) exp2f(x)
#endif
#if __has_builtin(__builtin_amdgcn_rcpf)
  #define RCPF(x) __builtin_amdgcn_rcpf(x)
#else
  #define RCPF(x) (1.0f/(x))
#endif

template<int CTRL>
__device__ __forceinline__ float dpp_add(float x) {
    int y = __builtin_amdgcn_update_dpp(0, __float_as_int(x), CTRL, 0xF, 0xF, true);
    return x + __int_as_float(y);
}

__device__ __forceinline__ v2f vfma(v2f a, v2f b, v2f c) {
#if __has_builtin(__builtin_elementwise_fma)
    return __builtin_elementwise_fma(a, b, c);
#else
    v2f r; r.x = fmaf(a.x, b.x, c.x); r.y = fmaf(a.y, b.y, c.y); return r;
#endif
}
__device__ __forceinline__ v2f splat(float x) { v2f v; v.x = x; v.y = x; return v; }

__global__ __launch_bounds__(256, 1) void ode_scan(
    const float* __restrict__ t,
    const float* __restrict__ Vs,
    const float* __restrict__ Tm,
    const float* __restrict__ C0,
    const float* __restrict__ R0,
    const float* __restrict__ W1,   // (5,10)
    const float* __restrict__ b1,   // (10)
    const float* __restrict__ W2,   // (10,5)
    const float* __restrict__ b2,   // (5)
    float* __restrict__ out,        // (B, N+1, 2)
    int B, int N)
{
    int tid = blockIdx.x * blockDim.x + threadIdx.x;
    int e = tid >> 3;
    int u = tid & 7;
    if (e >= B) return;

    const float S   = 2.88539008177792681472f;   // 2*log2(e)
    const float LN2 = 0.69314718055994530942f;
    float Vv = Vs[e], Tv = Tm[e];

    // Packed per-lane weights for hidden units j0=2u (x), j1=2u+1 (y).
    v2f W0p, W3p, W4p, CCp, V3p, V4p;
    {
        int j0 = 2*u, j1 = 2*u + 1;
        if (j0 < 10) {
            W0p.x = S*W1[j0]; W3p.x = S*W1[30+j0]; W4p.x = S*W1[40+j0];
            CCp.x = S*fmaf(Vv, W1[10+j0], fmaf(Tv, W1[20+j0], b1[j0]));
            V3p.x = -2.0f*W2[5*j0+3]; V4p.x = -2.0f*W2[5*j0+4];
        } else { W0p.x=0.f; W3p.x=0.f; W4p.x=0.f; CCp.x=-60.f; V3p.x=0.f; V4p.x=0.f; }
        if (j1 < 10) {
            W0p.y = S*W1[j1]; W3p.y = S*W1[30+j1]; W4p.y = S*W1[40+j1];
            CCp.y = S*fmaf(Vv, W1[10+j1], fmaf(Tv, W1[20+j1], b1[j1]));
            V3p.y = -2.0f*W2[5*j1+3]; V4p.y = -2.0f*W2[5*j1+4];
        } else { W0p.y=0.f; W3p.y=0.f; W4p.y=0.f; CCp.y=-60.f; V3p.y=0.f; V4p.y=0.f; }
        if (j0 == 10) {
            // constant unit: a=-60 -> z=2^-60 -> 1+z==1.0f -> r==1.0 exactly;
            // fast advance: s = r*r - r = 0 -> q3,q4,r stay exactly constant.
            float c3 = b2[3], c4 = b2[4];
            for (int j = 0; j < 10; ++j) { c3 += W2[5*j+3]; c4 += W2[5*j+4]; }
            V3p.x = c3; V4p.x = c4;
        }
    }

    const v2f ONEv = splat(1.0f);
    // ln2-scaled weights for the a-space advance (dl = ln2 * delta_a)
    v2f W0a = splat(LN2) * W0p;
    v2f W3a = splat(LN2) * W3p;
    v2f W4a = splat(LN2) * W4p;

    float Cap = C0[e], Res = R0[e];
    const float* trow = t + (size_t)e * (N + 1);
    float* orow = out + (size_t)e * (size_t)(N + 1) * 2;
    *(float2*)orow = make_float2(Cap, Res);
    float tprev = trow[0];

    v2f r = ONEv, q3 = V3p, q4 = V4p;   // valid after first (slow) step

    auto reduce_pair = [&](float& p3, float& p4) {
        p3 = q3.x + q3.y;
        p4 = q4.x + q4.y;
        p3 = dpp_add<0xB1>(p3);  p4 = dpp_add<0xB1>(p4);
        p3 = dpp_add<0x4E>(p3);  p4 = dpp_add<0x4E>(p4);
        p3 = dpp_add<0x141>(p3); p4 = dpp_add<0x141>(p4);
    };

    // exact step: recompute r (and q3,q4) from scratch -> kills drift
    auto slow_step = [&](float tn, float2& dst) {
        v2f TP = vfma(splat(tprev), W0p, CCp);
        v2f A  = vfma(splat(Res), W4p, vfma(splat(Cap), W3p, TP));
        v2f zz; zz.x = EXP2F(A.x); zz.y = EXP2F(A.y);
        v2f d = zz + ONEv;
        v2f rr; rr.x = RCPF(d.x); rr.y = RCPF(d.y);
        r  = rr;
        q3 = r * V3p;
        q4 = r * V4p;
        float h = tn - tprev;
        float p3, p4;
        reduce_pair(p3, p4);
        Cap = fmaf(h, p3, Cap);
        Res = fmaf(h, p4, Res);
        tprev = tn;
        dst = make_float2(Cap, Res);
    };

    // incremental step: advance q3,q4 (and r) by 2nd-order Taylor in a-space.
    // Off-chain prep: s = r^2-r, rm = r-1/2, sv3 = s*V3, sv4 = s*V4.
    // On-chain: p3,p4 -> G -> dl -> {f, dl*sv3, dl*sv4, dl*s} -> q3',q4',r'.
    auto fast_step = [&](float tn, float2& dst) {
        float h = tn - tprev;
        v2f s   = vfma(r, r, -r);
        v2f rm  = r + splat(-0.5f);
        v2f sv3 = s * V3p;
        v2f sv4 = s * V4p;
        float p3, p4;
        reduce_pair(p3, p4);
        Cap = fmaf(h, p3, Cap);     // off the cross-step chain
        Res = fmaf(h, p4, Res);
        tprev = tn;
        dst = make_float2(Cap, Res);
        v2f G  = vfma(splat(p3), W3a, vfma(splat(p4), W4a, W0a));
        v2f dl = splat(h) * G;
        v2f f  = vfma(dl, rm, ONEv);
        q3 = vfma(dl * sv3, f, q3);
        q4 = vfma(dl * sv4, f, q4);
        r  = vfma(dl * s,   f, r);
    };

    int i = 1;
    if (N >= 2*CH) {
        float rawA[CH], rawB[CH];
        float2 keep[CH];
        int nch = N / CH;
        int npair = nch / 2;
        int lim = N + 1 - CH;

#pragma unroll
        for (int m = 0; m < CH; ++m) rawA[m] = trow[1 + m];   // chunk 0

        float2* op = (float2*)orow + 1;
        for (int p = 0; p < npair; ++p) {
            int c = 2*p;
            {   // process chunk c (rawA), prefetch chunk c+1 into rawB
                int base = (c + 1)*CH + 1; if (base > lim) base = lim;
                const float* lp = trow + base;
#pragma unroll
                for (int m = 0; m < CH; ++m) {
                    rawB[m] = lp[m];
                    if ((m % RS) == 0) slow_step(rawA[m], keep[m]);
                    else               fast_step(rawA[m], keep[m]);
                }
#pragma unroll
                for (int m = 0; m < CH; ++m) op[m] = keep[m];   // store burst
                op += CH;
            }
            {   // process chunk c+1 (rawB), prefetch chunk c+2 into rawA
                int base = (c + 2)*CH + 1; if (base > lim) base = lim;
                const float* lp = trow + base;
#pragma unroll
                for (int m = 0; m < CH; ++m) {
                    rawA[m] = lp[m];
                    if ((m % RS) == 0) slow_step(rawB[m], keep[m]);
                    else               fast_step(rawB[m], keep[m]);
                }
#pragma unroll
                for (int m = 0; m < CH; ++m) op[m] = keep[m];   // store burst
                op += CH;
            }
        }
        i = 2*CH*npair + 1;
    }
    // scalar tail (not hit for N=2048): all exact steps
    for (; i <= N; ++i) {
        slow_step(trow[i], *(float2*)(orow + 2*(size_t)i));
    }
}

extern "C" void kernel_launch(void* const* d_in, const int* in_sizes, int n_in,
                              void* d_out, int out_size, void* d_ws, size_t ws_size,
                              hipStream_t stream) {
    const float* t  = (const float*)d_in[0];
    const float* Vs = (const float*)d_in[1];
    const float* Tm = (const float*)d_in[2];
    const float* C0 = (const float*)d_in[3];
    const float* R0 = (const float*)d_in[4];
    const float* W1 = (const float*)d_in[5];
    const float* b1 = (const float*)d_in[6];
    const float* W2 = (const float*)d_in[7];
    const float* b2 = (const float*)d_in[8];
    float* out = (float*)d_out;

    int B = in_sizes[1];
    int N = in_sizes[0] / B - 1;

    int threads = B * LPE;
    dim3 block(256);
    dim3 grid((threads + 255) / 256);
    hipLaunchKernelGGL(ode_scan, grid, block, 0, stream,
                       t, Vs, Tm, C0, R0, W1, b1, W2, b2, out, B, N);
}

// Round 9
// 119.204 us; speedup vs baseline: 1.2452x; 1.2452x over previous
//
#include <hip/hip_runtime.h>

// 8 lanes per batch element; 2 hidden units per lane packed as float2 (VOP3P).
// Fast steps advance q3=r*V3, q4=r*V4 directly by a 2nd-order Taylor in a-space;
// exact exp2+rcp resync every RS steps. Chunk loop is split into
// load / compute / store phases with asm memory barriers so the 16-deep
// t-prefetch actually stays in registers (R4-R8 collapsed to ~6 in-flight).
#define LPE 8
#define CH 16   // steps per prefetch chunk
#define RS 4    // resync period (must divide CH)

typedef float v2f __attribute__((ext_vector_type(2)));

#if __has_builtin(__builtin_amdgcn_exp2f)
  #define EXP2F(x) __builtin_amdgcn_exp2f(x)
#else
  #define EXP2F(x) exp2f(x)
#endif
#if __has_builtin(__builtin_amdgcn_rcpf)
  #define RCPF(x) __builtin_amdgcn_rcpf(x)
#else
  #define RCPF(x) (1.0f/(x))
#endif

template<int CTRL>
__device__ __forceinline__ float dpp_add(float x) {
    int y = __builtin_amdgcn_update_dpp(0, __float_as_int(x), CTRL, 0xF, 0xF, true);
    return x + __int_as_float(y);
}

__device__ __forceinline__ v2f vfma(v2f a, v2f b, v2f c) {
#if __has_builtin(__builtin_elementwise_fma)
    return __builtin_elementwise_fma(a, b, c);
#else
    v2f r; r.x = fmaf(a.x, b.x, c.x); r.y = fmaf(a.y, b.y, c.y); return r;
#endif
}
__device__ __forceinline__ v2f splat(float x) { v2f v; v.x = x; v.y = x; return v; }

#define MEMBAR() __asm__ __volatile__("" ::: "memory")

__global__ __launch_bounds__(256, 1) void ode_scan(
    const float* __restrict__ t,
    const float* __restrict__ Vs,
    const float* __restrict__ Tm,
    const float* __restrict__ C0,
    const float* __restrict__ R0,
    const float* __restrict__ W1,   // (5,10)
    const float* __restrict__ b1,   // (10)
    const float* __restrict__ W2,   // (10,5)
    const float* __restrict__ b2,   // (5)
    float* __restrict__ out,        // (B, N+1, 2)
    int B, int N)
{
    int tid = blockIdx.x * blockDim.x + threadIdx.x;
    int e = tid >> 3;
    int u = tid & 7;
    if (e >= B) return;

    const float S   = 2.88539008177792681472f;   // 2*log2(e)
    const float LN2 = 0.69314718055994530942f;
    float Vv = Vs[e], Tv = Tm[e];

    // Packed per-lane weights for hidden units j0=2u (x), j1=2u+1 (y).
    v2f W0p, W3p, W4p, CCp, V3p, V4p;
    {
        int j0 = 2*u, j1 = 2*u + 1;
        if (j0 < 10) {
            W0p.x = S*W1[j0]; W3p.x = S*W1[30+j0]; W4p.x = S*W1[40+j0];
            CCp.x = S*fmaf(Vv, W1[10+j0], fmaf(Tv, W1[20+j0], b1[j0]));
            V3p.x = -2.0f*W2[5*j0+3]; V4p.x = -2.0f*W2[5*j0+4];
        } else { W0p.x=0.f; W3p.x=0.f; W4p.x=0.f; CCp.x=-60.f; V3p.x=0.f; V4p.x=0.f; }
        if (j1 < 10) {
            W0p.y = S*W1[j1]; W3p.y = S*W1[30+j1]; W4p.y = S*W1[40+j1];
            CCp.y = S*fmaf(Vv, W1[10+j1], fmaf(Tv, W1[20+j1], b1[j1]));
            V3p.y = -2.0f*W2[5*j1+3]; V4p.y = -2.0f*W2[5*j1+4];
        } else { W0p.y=0.f; W3p.y=0.f; W4p.y=0.f; CCp.y=-60.f; V3p.y=0.f; V4p.y=0.f; }
        if (j0 == 10) {
            // constant unit: a=-60 -> z=2^-60 -> 1+z==1.0f -> r==1.0 exactly;
            // fast advance: s = r*r - r = 0 -> q3,q4,r stay exactly constant.
            float c3 = b2[3], c4 = b2[4];
            for (int j = 0; j < 10; ++j) { c3 += W2[5*j+3]; c4 += W2[5*j+4]; }
            V3p.x = c3; V4p.x = c4;
        }
    }

    const v2f ONEv = splat(1.0f);
    // ln2-scaled weights for the a-space advance (dl = ln2 * delta_a)
    v2f W0a = splat(LN2) * W0p;
    v2f W3a = splat(LN2) * W3p;
    v2f W4a = splat(LN2) * W4p;

    float Cap = C0[e], Res = R0[e];
    const float* trow = t + (size_t)e * (N + 1);
    float* orow = out + (size_t)e * (size_t)(N + 1) * 2;
    *(float2*)orow = make_float2(Cap, Res);
    float tprev = trow[0];

    v2f r = ONEv, q3 = V3p, q4 = V4p;   // valid after first (slow) step

    auto reduce_pair = [&](float& p3, float& p4) {
        p3 = q3.x + q3.y;
        p4 = q4.x + q4.y;
        p3 = dpp_add<0xB1>(p3);  p4 = dpp_add<0xB1>(p4);
        p3 = dpp_add<0x4E>(p3);  p4 = dpp_add<0x4E>(p4);
        p3 = dpp_add<0x141>(p3); p4 = dpp_add<0x141>(p4);
    };

    // exact step: recompute r (and q3,q4) from scratch -> kills drift
    auto slow_step = [&](float tn, float2& dst) {
        v2f TP = vfma(splat(tprev), W0p, CCp);
        v2f A  = vfma(splat(Res), W4p, vfma(splat(Cap), W3p, TP));
        v2f zz; zz.x = EXP2F(A.x); zz.y = EXP2F(A.y);
        v2f d = zz + ONEv;
        v2f rr; rr.x = RCPF(d.x); rr.y = RCPF(d.y);
        r  = rr;
        q3 = r * V3p;
        q4 = r * V4p;
        float h = tn - tprev;
        float p3, p4;
        reduce_pair(p3, p4);
        Cap = fmaf(h, p3, Cap);
        Res = fmaf(h, p4, Res);
        tprev = tn;
        dst = make_float2(Cap, Res);
    };

    // incremental step: advance q3,q4 (and r) by 2nd-order Taylor in a-space.
    auto fast_step = [&](float tn, float2& dst) {
        float h = tn - tprev;
        v2f s   = vfma(r, r, -r);
        v2f rm  = r + splat(-0.5f);
        v2f sv3 = s * V3p;
        v2f sv4 = s * V4p;
        float p3, p4;
        reduce_pair(p3, p4);
        Cap = fmaf(h, p3, Cap);     // off the cross-step chain
        Res = fmaf(h, p4, Res);
        tprev = tn;
        dst = make_float2(Cap, Res);
        v2f G  = vfma(splat(p3), W3a, vfma(splat(p4), W4a, W0a));
        v2f dl = splat(h) * G;
        v2f f  = vfma(dl, rm, ONEv);
        q3 = vfma(dl * sv3, f, q3);
        q4 = vfma(dl * sv4, f, q4);
        r  = vfma(dl * s,   f, r);
    };

    int i = 1;
    if (N >= 2*CH) {
        float rawA[CH], rawB[CH];
        float2 keep[CH];
        int nch = N / CH;
        int npair = nch / 2;
        int lim = N + 1 - CH;

#pragma unroll
        for (int m = 0; m < CH; ++m) rawA[m] = trow[1 + m];   // chunk 0
        MEMBAR();

        float2* op = (float2*)orow + 1;
        for (int p = 0; p < npair; ++p) {
            int c = 2*p;
            {   // loads for chunk c+1 -> compute chunk c -> store burst
                int base = (c + 1)*CH + 1; if (base > lim) base = lim;
                const float* lp = trow + base;
#pragma unroll
                for (int m = 0; m < CH; ++m) rawB[m] = lp[m];
                MEMBAR();
#pragma unroll
                for (int m = 0; m < CH; ++m) {
                    if ((m % RS) == 0) slow_step(rawA[m], keep[m]);
                    else               fast_step(rawA[m], keep[m]);
                }
                MEMBAR();
#pragma unroll
                for (int m = 0; m < CH; ++m) op[m] = keep[m];
                op += CH;
            }
            {   // loads for chunk c+2 -> compute chunk c+1 -> store burst
                int base = (c + 2)*CH + 1; if (base > lim) base = lim;
                const float* lp = trow + base;
#pragma unroll
                for (int m = 0; m < CH; ++m) rawA[m] = lp[m];
                MEMBAR();
#pragma unroll
                for (int m = 0; m < CH; ++m) {
                    if ((m % RS) == 0) slow_step(rawB[m], keep[m]);
                    else               fast_step(rawB[m], keep[m]);
                }
                MEMBAR();
#pragma unroll
                for (int m = 0; m < CH; ++m) op[m] = keep[m];
                op += CH;
            }
        }
        i = 2*CH*npair + 1;
    }
    // scalar tail (not hit for N=2048): all exact steps
    for (; i <= N; ++i) {
        slow_step(trow[i], *(float2*)(orow + 2*(size_t)i));
    }
}

extern "C" void kernel_launch(void* const* d_in, const int* in_sizes, int n_in,
                              void* d_out, int out_size, void* d_ws, size_t ws_size,
                              hipStream_t stream) {
    const float* t  = (const float*)d_in[0];
    const float* Vs = (const float*)d_in[1];
    const float* Tm = (const float*)d_in[2];
    const float* C0 = (const float*)d_in[3];
    const float* R0 = (const float*)d_in[4];
    const float* W1 = (const float*)d_in[5];
    const float* b1 = (const float*)d_in[6];
    const float* W2 = (const float*)d_in[7];
    const float* b2 = (const float*)d_in[8];
    float* out = (float*)d_out;

    int B = in_sizes[1];
    int N = in_sizes[0] / B - 1;

    int threads = B * LPE;
    dim3 block(256);
    dim3 grid((threads + 255) / 256);
    hipLaunchKernelGGL(ode_scan, grid, block, 0, stream,
                       t, Vs, Tm, C0, R0, W1, b1, W2, b2, out, B, N);
}